// Round 22
// baseline (237.454 us; speedup 1.0000x reference)
//
#include <hip/hip_runtime.h>

#define B 2048
#define NF 39
#define D 16

typedef __bf16 bf16x8 __attribute__((ext_vector_type(8)));
typedef float f32x4 __attribute__((ext_vector_type(4)));

// barrier with LDS-only drain: prefetched global loads stay in flight.
__device__ __forceinline__ void lds_barrier() {
  asm volatile("s_waitcnt lgkmcnt(0)" ::: "memory");
  __builtin_amdgcn_s_barrier();
}

// ---------------------------------------------------------------------------
// prep helpers. CIN: Wg[((c*13 + mt)*64 + l)*8 + j],
//   value = W[o = mt*16+(l&15)][k = c*32+(l>>4)*8+j], k = h*40+m padding.
// DNN: Wd[((c*25 + tt)*64 + l)*8 + j], K padded to nch*32.
// ---------------------------------------------------------------------------
__device__ __forceinline__ void prep_cin_one(const float* __restrict__ W,
                                             __bf16* __restrict__ Wg,
                                             int Hreal, int idx) {
  int l = idx & 63;
  int mt = (idx >> 6) % 13;
  int c = idx / (13 * 64);
  int o = mt * 16 + (l & 15);
  int kb = c * 32 + ((l >> 4) << 3);
  int rowlen = Hreal * 39;
  bf16x8 v;
#pragma unroll
  for (int j = 0; j < 8; ++j) {
    int k = kb + j;
    int h = k / 40;
    int m = k - h * 40;
    float val = 0.f;
    if (o < 200 && h < Hreal && m < 39) val = W[(long)o * rowlen + h * 39 + m];
    v[j] = (__bf16)val;
  }
  *reinterpret_cast<bf16x8*>(Wg + (long)idx * 8) = v;
}

__device__ __forceinline__ void prep_dnn_one(const float* __restrict__ W,
                                             __bf16* __restrict__ Wd,
                                             int IN, int idx) {
  int l = idx & 63;
  int tt = (idx >> 6) % 25;
  int c = idx / (25 * 64);
  int o = tt * 16 + (l & 15);
  int kb = c * 32 + ((l >> 4) << 3);
  bf16x8 v;
#pragma unroll
  for (int j = 0; j < 8; ++j) {
    int k = kb + j;
    v[j] = (k < IN) ? (__bf16)W[(long)o * IN + k] : (__bf16)0.f;
  }
  *reinterpret_cast<bf16x8*>(Wd + (long)idx * 8) = v;
}

#define PREP_T0 (50 * 13 * 64)
#define PREP_T12 (126 * 13 * 64)
#define PREP_T3 (20 * 25 * 64)
#define PREP_T4 (13 * 25 * 64)
#define PREP_TOTAL (PREP_T0 + 2 * PREP_T12 + PREP_T3 + PREP_T4)
#define PREP_BLOCKS ((PREP_TOTAL + 255) / 256)

// ---------------------------------------------------------------------------
// K1: merged gather (blocks 0..B-1) + weight prep (blocks B..)
// ---------------------------------------------------------------------------
__global__ __launch_bounds__(256) void gather_prep(
    const int* __restrict__ fid, const float* __restrict__ fval,
    const float* __restrict__ emb, const float* __restrict__ bias_emb,
    float* __restrict__ inputs, float* __restrict__ biassum,
    const float* __restrict__ cW0, const float* __restrict__ cW1,
    const float* __restrict__ cW2, const float* __restrict__ dW0,
    const float* __restrict__ dW1, __bf16* __restrict__ Wg0,
    __bf16* __restrict__ Wg1, __bf16* __restrict__ Wg2,
    __bf16* __restrict__ Wd0, __bf16* __restrict__ Wd1) {
  int t = threadIdx.x;
  if (blockIdx.x < B) {
    int b = blockIdx.x;
    __shared__ int ids[NF];
    __shared__ float vals[NF];
    if (t < NF) { ids[t] = fid[b * NF + t]; vals[t] = fval[b * NF + t]; }
    __syncthreads();
    for (int i = t; i < NF * D; i += 256) {
      int f = i >> 4, d = i & 15;
      inputs[b * NF * D + i] = emb[(long)ids[f] * D + d] * vals[f];
    }
    if (t < 64) {
      float pb = (t < NF) ? bias_emb[ids[t]] * vals[t] : 0.f;
#pragma unroll
      for (int m = 32; m >= 1; m >>= 1) pb += __shfl_xor(pb, m);
      if (t == 0) biassum[b] = pb;
    }
    return;
  }
  int idx = (blockIdx.x - B) * 256 + t;
  if (idx < PREP_T0) { prep_cin_one(cW0, Wg0, 39, idx); return; }
  idx -= PREP_T0;
  if (idx < PREP_T12) { prep_cin_one(cW1, Wg1, 100, idx); return; }
  idx -= PREP_T12;
  if (idx < PREP_T12) { prep_cin_one(cW2, Wg2, 100, idx); return; }
  idx -= PREP_T12;
  if (idx < PREP_T3) { prep_dnn_one(dW0, Wd0, 624, idx); return; }
  idx -= PREP_T3;
  if (idx < PREP_T4) prep_dnn_one(dW1, Wd1, 400, idx);
}

// ---------------------------------------------------------------------------
// K3: fused 3-layer CIN, PRODUCER/CONSUMER role split.
// Block = 4 b's (64 cols), 512 threads = 8 waves:
//   waves 0-3 CONSUMERS: exact r6 per-wave work (13 pairs, W reg-dbuf,
//     8 bfr ds_read, 26 MFMA) — no form_x.
//   waves 4-7 PRODUCERS: the 8 form_x/stage (2 per wave), filling X[s+1]
//     while consumers consume X[s].
// LDS-phase and MFMA-phase run in different waves CONCURRENTLY -> per-stage
// wall = max(pipes), not sum. Barrier counts identical across roles.
// X addr (bytes): col*128 + ((g*16) ^ ((col&7)<<4)), g = k-group 0..7.
// ---------------------------------------------------------------------------
__device__ __forceinline__ void form_x(const float* Hs, const float* Zs,
                                       __bf16* xbuf, int k0, int col) {
  int h = (int)((unsigned)k0 / 40u);
  int m0 = k0 - h * 40;
  float hv = Hs[h * 64 + col];
  const float4* zp = reinterpret_cast<const float4*>(Zs + col * 44 + m0);
  float4 za = zp[0], zb = zp[1];
  bf16x8 xv;
  xv[0] = (__bf16)(hv * za.x); xv[1] = (__bf16)(hv * za.y);
  xv[2] = (__bf16)(hv * za.z); xv[3] = (__bf16)(hv * za.w);
  xv[4] = (__bf16)(hv * zb.x); xv[5] = (__bf16)(hv * zb.y);
  xv[6] = (__bf16)(hv * zb.z); xv[7] = (__bf16)(hv * zb.w);
  int g = (k0 >> 3) & 7;
  *reinterpret_cast<bf16x8*>(
      reinterpret_cast<char*>(xbuf) + col * 128 + ((g * 16) ^ ((col & 7) << 4))) = xv;
}

template <int NW, int NST, int SPLIT>
__device__ __forceinline__ void cin_consumer(
    float* Hs, const float* Zs, __bf16* Xs,
    const __bf16* __restrict__ Wg, const float* __restrict__ bias,
    float* __restrict__ cin_out, int col_offset, int bbase, int l) {
  constexpr int TLO = (13 * NW) >> 2;  // 0,3,6,9
  const int q = l >> 4, dd = l & 15;

  f32x4 acc[13] = {};
  bf16x8 wf[8], wfn[8];
  const __bf16* wp = Wg + l * 8 + TLO * 512;
#pragma unroll
  for (int i = 0; i < 4; ++i)
#pragma unroll
    for (int hf = 0; hf < 2; ++hf)
      wf[i * 2 + hf] = *reinterpret_cast<const bf16x8*>(wp + hf * 6656 + i * 512);

  lds_barrier();  // producers finished X[0]

  for (int s = 0; s < NST; ++s) {
    __bf16* xcur = Xs + (s & 1) * 4096;
    const bool more = (s + 1 < NST);
    if (more) {
      const __bf16* wq = wp + 13312;
#pragma unroll
      for (int i = 0; i < 4; ++i)
#pragma unroll
        for (int hf = 0; hf < 2; ++hf)
          wfn[i * 2 + hf] =
              *reinterpret_cast<const bf16x8*>(wq + hf * 6656 + i * 512);
    }
    bf16x8 bfr[4][2];
#pragma unroll
    for (int f = 0; f < 4; ++f)
#pragma unroll
      for (int hf = 0; hf < 2; ++hf) {
        int col = f * 16 + dd;
        int g = q + hf * 4;
        bfr[f][hf] = *reinterpret_cast<const bf16x8*>(
            reinterpret_cast<const char*>(xcur) + col * 128 +
            ((g * 16) ^ ((col & 7) << 4)));
      }
    __builtin_amdgcn_s_setprio(1);
#pragma unroll
    for (int i = 0; i < 13; ++i) {
      const int p = 13 * NW + i;
      const int ti = (p >> 2) - TLO;
      const int f = p & 3;
      acc[i] = __builtin_amdgcn_mfma_f32_16x16x32_bf16(wf[ti * 2 + 0], bfr[f][0],
                                                       acc[i], 0, 0, 0);
      acc[i] = __builtin_amdgcn_mfma_f32_16x16x32_bf16(wf[ti * 2 + 1], bfr[f][1],
                                                       acc[i], 0, 0, 0);
    }
    __builtin_amdgcn_s_setprio(0);
    lds_barrier();
    if (more) {
#pragma unroll
      for (int i = 0; i < 8; ++i) wf[i] = wfn[i];
      wp += 13312;
    }
  }

  // epilogue: D layout col = dd, row = q*4 + r
#pragma unroll
  for (int i = 0; i < 13; ++i) {
    const int p = 13 * NW + i;
    const int tt = p >> 2, f = p & 3;
    const int b = bbase + f;
#pragma unroll
    for (int r = 0; r < 4; ++r) {
      int o = tt * 16 + q * 4 + r;
      if (o < 200) {
        float x = fmaxf(acc[i][r] + bias[o], 0.f);
        if (SPLIT && o < 100) {
          Hs[o * 64 + f * 16 + dd] = x;  // h_next stays in LDS
        } else {
          x += __shfl_xor(x, 1);
          x += __shfl_xor(x, 2);
          x += __shfl_xor(x, 4);
          x += __shfl_xor(x, 8);
          if (dd == 0) cin_out[b * 400 + col_offset + o - (SPLIT ? 100 : 0)] = x;
        }
      }
    }
  }
  lds_barrier();
}

template <int PG, int NST>
__device__ __forceinline__ void cin_producer(const float* Hs, const float* Zs,
                                             __bf16* Xs, int l) {
  form_x(Hs, Zs, Xs, PG * 8, l);
  form_x(Hs, Zs, Xs, (PG + 4) * 8, l);
  lds_barrier();  // X[0] ready
  for (int s = 0; s < NST; ++s) {
    if (s + 1 < NST) {
      __bf16* xnxt = Xs + ((s + 1) & 1) * 4096;
      form_x(Hs, Zs, xnxt, (s + 1) * 64 + PG * 8, l);
      form_x(Hs, Zs, xnxt, (s + 1) * 64 + (PG + 4) * 8, l);
    }
    lds_barrier();
  }
  lds_barrier();  // consumers' epilogue (Hs update for next layer)
}

template <int NW>
__device__ __forceinline__ void cin_cons_all(
    float* Hs, const float* Zs, __bf16* Xs, const __bf16* Wg0,
    const __bf16* Wg1, const __bf16* Wg2, const float* cb0, const float* cb1,
    const float* cb2, float* cinres, int bbase, int l) {
  cin_consumer<NW, 25, 1>(Hs, Zs, Xs, Wg0, cb0, cinres, 0, bbase, l);
  cin_consumer<NW, 63, 1>(Hs, Zs, Xs, Wg1, cb1, cinres, 100, bbase, l);
  cin_consumer<NW, 63, 0>(Hs, Zs, Xs, Wg2, cb2, cinres, 200, bbase, l);
}

template <int PG>
__device__ __forceinline__ void cin_prod_all(const float* Hs, const float* Zs,
                                             __bf16* Xs, int l) {
  cin_producer<PG, 25>(Hs, Zs, Xs, l);
  cin_producer<PG, 63>(Hs, Zs, Xs, l);
  cin_producer<PG, 63>(Hs, Zs, Xs, l);
}

__global__ __launch_bounds__(512, 2) void cin_pc(
    const float* __restrict__ Zin, const __bf16* __restrict__ Wg0,
    const __bf16* __restrict__ Wg1, const __bf16* __restrict__ Wg2,
    const float* __restrict__ cb0, const float* __restrict__ cb1,
    const float* __restrict__ cb2, float* __restrict__ cinres) {
  __shared__ float Hs[101 * 64];      // [h][col]; layer0 rows 0..40 = Z^T
  __shared__ float Zs[64 * 44];       // [col][m], m=39 zero pad
  __shared__ __bf16 Xs[2 * 64 * 64];  // double-buffered X, swizzled
  const int t = threadIdx.x;
  const int bbase = blockIdx.x * 4;

  for (int i = t; i < 64 * 40; i += 512) {
    int col = i / 40, m = i - (i / 40) * 40;
    int b = bbase + (col >> 4), d = col & 15;
    Zs[col * 44 + m] = (m < NF) ? Zin[((long)b * NF + m) * 16 + d] : 0.f;
  }
  for (int i = t; i < 41 * 64; i += 512) {
    int h = i >> 6, col = i & 63;
    int b = bbase + (col >> 4), d = col & 15;
    Hs[i] = (h < NF) ? Zin[((long)b * NF + h) * 16 + d] : 0.f;
  }
  if (t < 64) Hs[100 * 64 + t] = 0.f;  // pad row for layers 1/2
  __syncthreads();

  const int w = t >> 6;
  const int l = t & 63;
  switch (w) {
    case 0: cin_cons_all<0>(Hs, Zs, Xs, Wg0, Wg1, Wg2, cb0, cb1, cb2, cinres, bbase, l); break;
    case 1: cin_cons_all<1>(Hs, Zs, Xs, Wg0, Wg1, Wg2, cb0, cb1, cb2, cinres, bbase, l); break;
    case 2: cin_cons_all<2>(Hs, Zs, Xs, Wg0, Wg1, Wg2, cb0, cb1, cb2, cinres, bbase, l); break;
    case 3: cin_cons_all<3>(Hs, Zs, Xs, Wg0, Wg1, Wg2, cb0, cb1, cb2, cinres, bbase, l); break;
    case 4: cin_prod_all<0>(Hs, Zs, Xs, l); break;
    case 5: cin_prod_all<1>(Hs, Zs, Xs, l); break;
    case 6: cin_prod_all<2>(Hs, Zs, Xs, l); break;
    default: cin_prod_all<3>(Hs, Zs, Xs, l); break;
  }
}

// ---------------------------------------------------------------------------
// K4: DNN via MFMA. Grid = 32 bg x 25 tiles = 800 blocks.
// ---------------------------------------------------------------------------
template <int IN>
__device__ __forceinline__ void dnn_stage_load(const float* __restrict__ x,
                                               int bg, int c, int t,
                                               float4& a, float4& b2) {
  int b = t >> 2, kb = t & 3;
  int k0 = c * 32 + kb * 8;
  if (k0 < IN) {
    const float4* p =
        reinterpret_cast<const float4*>(x + (long)(bg * 64 + b) * IN + k0);
    a = p[0];
    b2 = p[1];
  } else {
    a = make_float4(0.f, 0.f, 0.f, 0.f);
    b2 = make_float4(0.f, 0.f, 0.f, 0.f);
  }
}

__device__ __forceinline__ void dnn_stage_write(__bf16* Xs, int t, float4 a,
                                                float4 b2) {
  int b = t >> 2, kb = t & 3;
  bf16x8 v;
  v[0] = (__bf16)a.x;  v[1] = (__bf16)a.y;  v[2] = (__bf16)a.z;  v[3] = (__bf16)a.w;
  v[4] = (__bf16)b2.x; v[5] = (__bf16)b2.y; v[6] = (__bf16)b2.z; v[7] = (__bf16)b2.w;
  *reinterpret_cast<bf16x8*>(Xs + ((kb * 64 + b) << 3)) = v;
}

template <int IN, int NCH>
__global__ __launch_bounds__(256) void dnn_mfma2(
    const float* __restrict__ x, const __bf16* __restrict__ Wd,
    const float* __restrict__ bias, float* __restrict__ out) {
  __shared__ __bf16 Xs[2 * 2048];
  const int bg = blockIdx.x / 25;
  const int tile = blockIdx.x - bg * 25;
  const int t = threadIdx.x;
  const int w = t >> 6, l = t & 63;
  const int q = l >> 4, dd = l & 15;
  const __bf16* wl = Wd + l * 8;

  f32x4 acc = {};
  bf16x8 wf = *reinterpret_cast<const bf16x8*>(wl + (long)(tile * 64) * 8);

  float4 ra, rb;
  dnn_stage_load<IN>(x, bg, 0, t, ra, rb);
  dnn_stage_write(Xs, t, ra, rb);
  lds_barrier();

  for (int c = 0; c < NCH; ++c) {
    __bf16* cur = Xs + (c & 1) * 2048;
    __bf16* nxt = Xs + ((c + 1) & 1) * 2048;
    const bool more = (c + 1 < NCH);
    bf16x8 wfn;
    if (more) {
      dnn_stage_load<IN>(x, bg, c + 1, t, ra, rb);
      wfn = *reinterpret_cast<const bf16x8*>(
          wl + (long)(((c + 1) * 25 + tile) * 64) * 8);
    }
    bf16x8 bfr = *reinterpret_cast<const bf16x8*>(cur + ((q * 64 + w * 16 + dd) << 3));
    acc = __builtin_amdgcn_mfma_f32_16x16x32_bf16(wf, bfr, acc, 0, 0, 0);
    if (more) dnn_stage_write(nxt, t, ra, rb);
    lds_barrier();
    if (more) wf = wfn;
  }

  const int b = bg * 64 + w * 16 + dd;
#pragma unroll
  for (int r = 0; r < 4; ++r) {
    int o = tile * 16 + q * 4 + r;
    out[(long)b * 400 + o] = fmaxf(acc[r] + bias[o], 0.f);
  }
}

// ---------------------------------------------------------------------------
// K5: final FC + bias-embedding sum
// ---------------------------------------------------------------------------
__global__ __launch_bounds__(256) void final_kernel(
    const float* __restrict__ cin, const float* __restrict__ d1,
    const float* __restrict__ fcW, const float* __restrict__ fcb,
    const float* __restrict__ biassum, float* __restrict__ out) {
  int b = blockIdx.x, t = threadIdx.x;
  float p = 0.f;
  for (int i = t; i < 800; i += 256) {
    float v = (i < 400) ? cin[b * 400 + i] : d1[b * 400 + (i - 400)];
    p += v * fcW[i];
  }
#pragma unroll
  for (int m = 32; m >= 1; m >>= 1) p += __shfl_xor(p, m);
  __shared__ float red[4];
  if ((t & 63) == 0) red[t >> 6] = p;
  __syncthreads();
  if (t == 0) out[b] = red[0] + red[1] + red[2] + red[3] + fcb[0] + biassum[b];
}

// ---------------------------------------------------------------------------
extern "C" void kernel_launch(void* const* d_in, const int* in_sizes, int n_in,
                              void* d_out, int out_size, void* d_ws,
                              size_t ws_size, hipStream_t stream) {
  (void)in_sizes; (void)n_in; (void)out_size; (void)ws_size;
  const int* fid = (const int*)d_in[0];
  const float* fval = (const float*)d_in[1];
  const float* emb = (const float*)d_in[2];
  const float* bias_emb = (const float*)d_in[3];
  const float* cW0 = (const float*)d_in[4];
  const float* cb0 = (const float*)d_in[5];
  const float* cW1 = (const float*)d_in[6];
  const float* cb1 = (const float*)d_in[7];
  const float* cW2 = (const float*)d_in[8];
  const float* cb2 = (const float*)d_in[9];
  const float* dW0 = (const float*)d_in[10];
  const float* db0 = (const float*)d_in[11];
  const float* dW1 = (const float*)d_in[12];
  const float* db1 = (const float*)d_in[13];
  const float* fcW = (const float*)d_in[14];
  const float* fcb = (const float*)d_in[15];
  float* out = (float*)d_out;

  float* ws = (float*)d_ws;
  float* inputs = ws;  ws += B * NF * D;
  float* biassum = ws; ws += B;
  float* cinres = ws;  ws += B * 400;
  float* dd0 = ws;     ws += B * 400;
  float* dd1 = ws;     ws += B * 400;
  __bf16* Wg0 = (__bf16*)ws; ws += (50 * 13 * 64 * 8) / 2;
  __bf16* Wg1 = (__bf16*)ws; ws += (126 * 13 * 64 * 8) / 2;
  __bf16* Wg2 = (__bf16*)ws; ws += (126 * 13 * 64 * 8) / 2;
  __bf16* Wd0 = (__bf16*)ws; ws += (20 * 25 * 64 * 8) / 2;
  __bf16* Wd1 = (__bf16*)ws; ws += (13 * 25 * 64 * 8) / 2;

  gather_prep<<<B + PREP_BLOCKS, 256, 0, stream>>>(
      fid, fval, emb, bias_emb, inputs, biassum,
      cW0, cW1, cW2, dW0, dW1, Wg0, Wg1, Wg2, Wd0, Wd1);

  cin_pc<<<B / 4, 512, 0, stream>>>(inputs, Wg0, Wg1, Wg2, cb0, cb1, cb2, cinres);

  dnn_mfma2<624, 20><<<800, 256, 0, stream>>>(inputs, Wd0, db0, dd0);
  dnn_mfma2<400, 13><<<800, 256, 0, stream>>>(dd0, Wd1, db1, dd1);

  final_kernel<<<B, 256, 0, stream>>>(cinres, dd1, fcW, fcb, biassum, out);
}

// Round 23
// 196.377 us; speedup vs baseline: 1.2092x; 1.2092x over previous
//
#include <hip/hip_runtime.h>

#define B 2048
#define NF 39
#define D 16

typedef __bf16 bf16x8 __attribute__((ext_vector_type(8)));
typedef float f32x4 __attribute__((ext_vector_type(4)));

// barrier with LDS-only drain: prefetched global loads stay in flight.
__device__ __forceinline__ void lds_barrier() {
  asm volatile("s_waitcnt lgkmcnt(0)" ::: "memory");
  __builtin_amdgcn_s_barrier();
}

// ---------------------------------------------------------------------------
// prep helpers. CIN: Wg[((c*13 + mt)*64 + l)*8 + j],
//   value = W[o = mt*16+(l&15)][k = c*32+(l>>4)*8+j], k = h*40+m padding.
// DNN: Wd[((c*25 + tt)*64 + l)*8 + j], K padded to nch*32.
// ---------------------------------------------------------------------------
__device__ __forceinline__ void prep_cin_one(const float* __restrict__ W,
                                             __bf16* __restrict__ Wg,
                                             int Hreal, int idx) {
  int l = idx & 63;
  int mt = (idx >> 6) % 13;
  int c = idx / (13 * 64);
  int o = mt * 16 + (l & 15);
  int kb = c * 32 + ((l >> 4) << 3);
  int rowlen = Hreal * 39;
  bf16x8 v;
#pragma unroll
  for (int j = 0; j < 8; ++j) {
    int k = kb + j;
    int h = k / 40;
    int m = k - h * 40;
    float val = 0.f;
    if (o < 200 && h < Hreal && m < 39) val = W[(long)o * rowlen + h * 39 + m];
    v[j] = (__bf16)val;
  }
  *reinterpret_cast<bf16x8*>(Wg + (long)idx * 8) = v;
}

__device__ __forceinline__ void prep_dnn_one(const float* __restrict__ W,
                                             __bf16* __restrict__ Wd,
                                             int IN, int idx) {
  int l = idx & 63;
  int tt = (idx >> 6) % 25;
  int c = idx / (25 * 64);
  int o = tt * 16 + (l & 15);
  int kb = c * 32 + ((l >> 4) << 3);
  bf16x8 v;
#pragma unroll
  for (int j = 0; j < 8; ++j) {
    int k = kb + j;
    v[j] = (k < IN) ? (__bf16)W[(long)o * IN + k] : (__bf16)0.f;
  }
  *reinterpret_cast<bf16x8*>(Wd + (long)idx * 8) = v;
}

#define PREP_T0 (50 * 13 * 64)
#define PREP_T12 (126 * 13 * 64)
#define PREP_T3 (20 * 25 * 64)
#define PREP_T4 (13 * 25 * 64)
#define PREP_TOTAL (PREP_T0 + 2 * PREP_T12 + PREP_T3 + PREP_T4)
#define PREP_BLOCKS ((PREP_TOTAL + 255) / 256)

// ---------------------------------------------------------------------------
// K1: merged gather (blocks 0..B-1) + weight prep (blocks B..) — independent
// work runs concurrently instead of in two serial dispatches.
// ---------------------------------------------------------------------------
__global__ __launch_bounds__(256) void gather_prep(
    const int* __restrict__ fid, const float* __restrict__ fval,
    const float* __restrict__ emb, const float* __restrict__ bias_emb,
    float* __restrict__ inputs, float* __restrict__ biassum,
    const float* __restrict__ cW0, const float* __restrict__ cW1,
    const float* __restrict__ cW2, const float* __restrict__ dW0,
    const float* __restrict__ dW1, __bf16* __restrict__ Wg0,
    __bf16* __restrict__ Wg1, __bf16* __restrict__ Wg2,
    __bf16* __restrict__ Wd0, __bf16* __restrict__ Wd1) {
  int t = threadIdx.x;
  if (blockIdx.x < B) {
    int b = blockIdx.x;
    __shared__ int ids[NF];
    __shared__ float vals[NF];
    if (t < NF) { ids[t] = fid[b * NF + t]; vals[t] = fval[b * NF + t]; }
    __syncthreads();
    for (int i = t; i < NF * D; i += 256) {
      int f = i >> 4, d = i & 15;
      inputs[b * NF * D + i] = emb[(long)ids[f] * D + d] * vals[f];
    }
    if (t < 64) {
      float pb = (t < NF) ? bias_emb[ids[t]] * vals[t] : 0.f;
#pragma unroll
      for (int m = 32; m >= 1; m >>= 1) pb += __shfl_xor(pb, m);
      if (t == 0) biassum[b] = pb;
    }
    return;
  }
  int idx = (blockIdx.x - B) * 256 + t;
  if (idx < PREP_T0) { prep_cin_one(cW0, Wg0, 39, idx); return; }
  idx -= PREP_T0;
  if (idx < PREP_T12) { prep_cin_one(cW1, Wg1, 100, idx); return; }
  idx -= PREP_T12;
  if (idx < PREP_T12) { prep_cin_one(cW2, Wg2, 100, idx); return; }
  idx -= PREP_T12;
  if (idx < PREP_T3) { prep_dnn_one(dW0, Wd0, 624, idx); return; }
  idx -= PREP_T3;
  if (idx < PREP_T4) prep_dnn_one(dW1, Wd1, 400, idx);
}

// ---------------------------------------------------------------------------
// K3: fused 3-layer CIN (exact r6/r15 structure — best measured, 172 us).
// Block = 4 b's (64 cols), 4 waves. h1/h2 live in LDS (Hs, f32).
// Per stage: 8 W global prefetch (reg dbuf, spans barriers), 8 bfr ds_read,
// 2 form_x (shared X build into dbuf LDS), 26 MFMA, lgkm-only barrier.
// X addr (bytes): col*128 + ((g*16) ^ ((col&7)<<4)), g = k-group 0..7.
// ---------------------------------------------------------------------------
__device__ __forceinline__ void form_x(const float* Hs, const float* Zs,
                                       __bf16* xbuf, int k0, int col) {
  int h = (int)((unsigned)k0 / 40u);
  int m0 = k0 - h * 40;
  float hv = Hs[h * 64 + col];
  const float4* zp = reinterpret_cast<const float4*>(Zs + col * 44 + m0);
  float4 za = zp[0], zb = zp[1];
  bf16x8 xv;
  xv[0] = (__bf16)(hv * za.x); xv[1] = (__bf16)(hv * za.y);
  xv[2] = (__bf16)(hv * za.z); xv[3] = (__bf16)(hv * za.w);
  xv[4] = (__bf16)(hv * zb.x); xv[5] = (__bf16)(hv * zb.y);
  xv[6] = (__bf16)(hv * zb.z); xv[7] = (__bf16)(hv * zb.w);
  int g = (k0 >> 3) & 7;
  *reinterpret_cast<bf16x8*>(
      reinterpret_cast<char*>(xbuf) + col * 128 + ((g * 16) ^ ((col & 7) << 4))) = xv;
}

template <int NW, int NST, int SPLIT>
__device__ __forceinline__ void cin_layer(
    float* Hs, const float* Zs, __bf16* Xs,
    const __bf16* __restrict__ Wg, const float* __restrict__ bias,
    float* __restrict__ cin_out, int col_offset, int bbase, int t) {
  constexpr int TLO = (13 * NW) >> 2;  // 0,3,6,9
  const int l = t & 63;
  const int q = l >> 4, dd = l & 15;

  f32x4 acc[13] = {};
  bf16x8 wf[8], wfn[8];
  const __bf16* wp = Wg + l * 8 + TLO * 512;
#pragma unroll
  for (int i = 0; i < 4; ++i)
#pragma unroll
    for (int hf = 0; hf < 2; ++hf)
      wf[i * 2 + hf] = *reinterpret_cast<const bf16x8*>(wp + hf * 6656 + i * 512);

  form_x(Hs, Zs, Xs, NW * 8, l);
  form_x(Hs, Zs, Xs, (NW + 4) * 8, l);
  lds_barrier();

  for (int s = 0; s < NST; ++s) {
    __bf16* xcur = Xs + (s & 1) * 4096;
    __bf16* xnxt = Xs + ((s + 1) & 1) * 4096;
    const bool more = (s + 1 < NST);
    if (more) {
      const __bf16* wq = wp + 13312;
#pragma unroll
      for (int i = 0; i < 4; ++i)
#pragma unroll
        for (int hf = 0; hf < 2; ++hf)
          wfn[i * 2 + hf] =
              *reinterpret_cast<const bf16x8*>(wq + hf * 6656 + i * 512);
    }
    bf16x8 bfr[4][2];
#pragma unroll
    for (int f = 0; f < 4; ++f)
#pragma unroll
      for (int hf = 0; hf < 2; ++hf) {
        int col = f * 16 + dd;
        int g = q + hf * 4;
        bfr[f][hf] = *reinterpret_cast<const bf16x8*>(
            reinterpret_cast<const char*>(xcur) + col * 128 +
            ((g * 16) ^ ((col & 7) << 4)));
      }
    if (more) {
      form_x(Hs, Zs, xnxt, (s + 1) * 64 + NW * 8, l);
      form_x(Hs, Zs, xnxt, (s + 1) * 64 + (NW + 4) * 8, l);
    }
    __builtin_amdgcn_s_setprio(1);
#pragma unroll
    for (int i = 0; i < 13; ++i) {
      const int p = 13 * NW + i;
      const int ti = (p >> 2) - TLO;
      const int f = p & 3;
      acc[i] = __builtin_amdgcn_mfma_f32_16x16x32_bf16(wf[ti * 2 + 0], bfr[f][0],
                                                       acc[i], 0, 0, 0);
      acc[i] = __builtin_amdgcn_mfma_f32_16x16x32_bf16(wf[ti * 2 + 1], bfr[f][1],
                                                       acc[i], 0, 0, 0);
    }
    __builtin_amdgcn_s_setprio(0);
    lds_barrier();
    if (more) {
#pragma unroll
      for (int i = 0; i < 8; ++i) wf[i] = wfn[i];
      wp += 13312;
    }
  }

  // epilogue: D layout col = dd, row = q*4 + r
#pragma unroll
  for (int i = 0; i < 13; ++i) {
    const int p = 13 * NW + i;
    const int tt = p >> 2, f = p & 3;
    const int b = bbase + f;
#pragma unroll
    for (int r = 0; r < 4; ++r) {
      int o = tt * 16 + q * 4 + r;
      if (o < 200) {
        float x = fmaxf(acc[i][r] + bias[o], 0.f);
        if (SPLIT && o < 100) {
          Hs[o * 64 + f * 16 + dd] = x;  // h_next stays in LDS
        } else {
          x += __shfl_xor(x, 1);
          x += __shfl_xor(x, 2);
          x += __shfl_xor(x, 4);
          x += __shfl_xor(x, 8);
          if (dd == 0) cin_out[b * 400 + col_offset + o - (SPLIT ? 100 : 0)] = x;
        }
      }
    }
  }
  lds_barrier();
}

template <int NW>
__device__ __forceinline__ void cin_all(
    float* Hs, const float* Zs, __bf16* Xs, const __bf16* Wg0,
    const __bf16* Wg1, const __bf16* Wg2, const float* cb0, const float* cb1,
    const float* cb2, float* cinres, int bbase, int t) {
  cin_layer<NW, 25, 1>(Hs, Zs, Xs, Wg0, cb0, cinres, 0, bbase, t);
  cin_layer<NW, 63, 1>(Hs, Zs, Xs, Wg1, cb1, cinres, 100, bbase, t);
  cin_layer<NW, 63, 0>(Hs, Zs, Xs, Wg2, cb2, cinres, 200, bbase, t);
}

__global__ __launch_bounds__(256, 2) void cin_fused(
    const float* __restrict__ Zin, const __bf16* __restrict__ Wg0,
    const __bf16* __restrict__ Wg1, const __bf16* __restrict__ Wg2,
    const float* __restrict__ cb0, const float* __restrict__ cb1,
    const float* __restrict__ cb2, float* __restrict__ cinres) {
  __shared__ float Hs[101 * 64];      // [h][col]; layer0 rows 0..40 = Z^T
  __shared__ float Zs[64 * 44];       // [col][m], m=39 zero pad
  __shared__ __bf16 Xs[2 * 64 * 64];  // double-buffered X, swizzled
  const int t = threadIdx.x;
  const int bbase = blockIdx.x * 4;

  for (int i = t; i < 64 * 40; i += 256) {
    int col = i / 40, m = i - (i / 40) * 40;
    int b = bbase + (col >> 4), d = col & 15;
    Zs[col * 44 + m] = (m < NF) ? Zin[((long)b * NF + m) * 16 + d] : 0.f;
  }
  for (int i = t; i < 41 * 64; i += 256) {
    int h = i >> 6, col = i & 63;
    int b = bbase + (col >> 4), d = col & 15;
    Hs[i] = (h < NF) ? Zin[((long)b * NF + h) * 16 + d] : 0.f;
  }
  if (t < 64) Hs[100 * 64 + t] = 0.f;  // pad row for layers 1/2
  __syncthreads();

  const int w = t >> 6;
  if (w == 0) cin_all<0>(Hs, Zs, Xs, Wg0, Wg1, Wg2, cb0, cb1, cb2, cinres, bbase, t);
  else if (w == 1) cin_all<1>(Hs, Zs, Xs, Wg0, Wg1, Wg2, cb0, cb1, cb2, cinres, bbase, t);
  else if (w == 2) cin_all<2>(Hs, Zs, Xs, Wg0, Wg1, Wg2, cb0, cb1, cb2, cinres, bbase, t);
  else cin_all<3>(Hs, Zs, Xs, Wg0, Wg1, Wg2, cb0, cb1, cb2, cinres, bbase, t);
}

// ---------------------------------------------------------------------------
// K4: DNN via MFMA. Grid = 32 bg x 25 tiles = 800 blocks (fills all CUs).
// ---------------------------------------------------------------------------
template <int IN>
__device__ __forceinline__ void dnn_stage_load(const float* __restrict__ x,
                                               int bg, int c, int t,
                                               float4& a, float4& b2) {
  int b = t >> 2, kb = t & 3;
  int k0 = c * 32 + kb * 8;
  if (k0 < IN) {
    const float4* p =
        reinterpret_cast<const float4*>(x + (long)(bg * 64 + b) * IN + k0);
    a = p[0];
    b2 = p[1];
  } else {
    a = make_float4(0.f, 0.f, 0.f, 0.f);
    b2 = make_float4(0.f, 0.f, 0.f, 0.f);
  }
}

__device__ __forceinline__ void dnn_stage_write(__bf16* Xs, int t, float4 a,
                                                float4 b2) {
  int b = t >> 2, kb = t & 3;
  bf16x8 v;
  v[0] = (__bf16)a.x;  v[1] = (__bf16)a.y;  v[2] = (__bf16)a.z;  v[3] = (__bf16)a.w;
  v[4] = (__bf16)b2.x; v[5] = (__bf16)b2.y; v[6] = (__bf16)b2.z; v[7] = (__bf16)b2.w;
  *reinterpret_cast<bf16x8*>(Xs + ((kb * 64 + b) << 3)) = v;
}

template <int IN, int NCH>
__global__ __launch_bounds__(256) void dnn_mfma2(
    const float* __restrict__ x, const __bf16* __restrict__ Wd,
    const float* __restrict__ bias, float* __restrict__ out) {
  __shared__ __bf16 Xs[2 * 2048];
  const int bg = blockIdx.x / 25;
  const int tile = blockIdx.x - bg * 25;
  const int t = threadIdx.x;
  const int w = t >> 6, l = t & 63;
  const int q = l >> 4, dd = l & 15;
  const __bf16* wl = Wd + l * 8;

  f32x4 acc = {};
  bf16x8 wf = *reinterpret_cast<const bf16x8*>(wl + (long)(tile * 64) * 8);

  float4 ra, rb;
  dnn_stage_load<IN>(x, bg, 0, t, ra, rb);
  dnn_stage_write(Xs, t, ra, rb);
  lds_barrier();

  for (int c = 0; c < NCH; ++c) {
    __bf16* cur = Xs + (c & 1) * 2048;
    __bf16* nxt = Xs + ((c + 1) & 1) * 2048;
    const bool more = (c + 1 < NCH);
    bf16x8 wfn;
    if (more) {
      dnn_stage_load<IN>(x, bg, c + 1, t, ra, rb);
      wfn = *reinterpret_cast<const bf16x8*>(
          wl + (long)(((c + 1) * 25 + tile) * 64) * 8);
    }
    bf16x8 bfr = *reinterpret_cast<const bf16x8*>(cur + ((q * 64 + w * 16 + dd) << 3));
    acc = __builtin_amdgcn_mfma_f32_16x16x32_bf16(wf, bfr, acc, 0, 0, 0);
    if (more) dnn_stage_write(nxt, t, ra, rb);
    lds_barrier();
    if (more) wf = wfn;
  }

  const int b = bg * 64 + w * 16 + dd;
#pragma unroll
  for (int r = 0; r < 4; ++r) {
    int o = tile * 16 + q * 4 + r;
    out[(long)b * 400 + o] = fmaxf(acc[r] + bias[o], 0.f);
  }
}

// ---------------------------------------------------------------------------
// K5: final FC + bias-embedding sum
// ---------------------------------------------------------------------------
__global__ __launch_bounds__(256) void final_kernel(
    const float* __restrict__ cin, const float* __restrict__ d1,
    const float* __restrict__ fcW, const float* __restrict__ fcb,
    const float* __restrict__ biassum, float* __restrict__ out) {
  int b = blockIdx.x, t = threadIdx.x;
  float p = 0.f;
  for (int i = t; i < 800; i += 256) {
    float v = (i < 400) ? cin[b * 400 + i] : d1[b * 400 + (i - 400)];
    p += v * fcW[i];
  }
#pragma unroll
  for (int m = 32; m >= 1; m >>= 1) p += __shfl_xor(p, m);
  __shared__ float red[4];
  if ((t & 63) == 0) red[t >> 6] = p;
  __syncthreads();
  if (t == 0) out[b] = red[0] + red[1] + red[2] + red[3] + fcb[0] + biassum[b];
}

// ---------------------------------------------------------------------------
extern "C" void kernel_launch(void* const* d_in, const int* in_sizes, int n_in,
                              void* d_out, int out_size, void* d_ws,
                              size_t ws_size, hipStream_t stream) {
  (void)in_sizes; (void)n_in; (void)out_size; (void)ws_size;
  const int* fid = (const int*)d_in[0];
  const float* fval = (const float*)d_in[1];
  const float* emb = (const float*)d_in[2];
  const float* bias_emb = (const float*)d_in[3];
  const float* cW0 = (const float*)d_in[4];
  const float* cb0 = (const float*)d_in[5];
  const float* cW1 = (const float*)d_in[6];
  const float* cb1 = (const float*)d_in[7];
  const float* cW2 = (const float*)d_in[8];
  const float* cb2 = (const float*)d_in[9];
  const float* dW0 = (const float*)d_in[10];
  const float* db0 = (const float*)d_in[11];
  const float* dW1 = (const float*)d_in[12];
  const float* db1 = (const float*)d_in[13];
  const float* fcW = (const float*)d_in[14];
  const float* fcb = (const float*)d_in[15];
  float* out = (float*)d_out;

  float* ws = (float*)d_ws;
  float* inputs = ws;  ws += B * NF * D;
  float* biassum = ws; ws += B;
  float* cinres = ws;  ws += B * 400;
  float* dd0 = ws;     ws += B * 400;
  float* dd1 = ws;     ws += B * 400;
  __bf16* Wg0 = (__bf16*)ws; ws += (50 * 13 * 64 * 8) / 2;
  __bf16* Wg1 = (__bf16*)ws; ws += (126 * 13 * 64 * 8) / 2;
  __bf16* Wg2 = (__bf16*)ws; ws += (126 * 13 * 64 * 8) / 2;
  __bf16* Wd0 = (__bf16*)ws; ws += (20 * 25 * 64 * 8) / 2;
  __bf16* Wd1 = (__bf16*)ws; ws += (13 * 25 * 64 * 8) / 2;

  gather_prep<<<B + PREP_BLOCKS, 256, 0, stream>>>(
      fid, fval, emb, bias_emb, inputs, biassum,
      cW0, cW1, cW2, dW0, dW1, Wg0, Wg1, Wg2, Wd0, Wd1);

  cin_fused<<<B / 4, 256, 0, stream>>>(inputs, Wg0, Wg1, Wg2, cb0, cb1, cb2, cinres);

  dnn_mfma2<624, 20><<<800, 256, 0, stream>>>(inputs, Wd0, db0, dd0);
  dnn_mfma2<400, 13><<<800, 256, 0, stream>>>(dd0, Wd1, db1, dd1);

  final_kernel<<<B, 256, 0, stream>>>(cinres, dd1, fcW, fcb, biassum, out);
}